// Round 9
// baseline (162.130 us; speedup 1.0000x reference)
//
#include <hip/hip_runtime.h>

#define NEG_SLOPE 0.01f
#define CAP 64        // logical capacity; P(deg>=64) ~ 1e-24
#define CAP_IN 16     // inline bucket: 16 x 4B = exactly one 64B line per node
#define CAP_OVF 48    // overflow region (pos 16..63)

typedef __attribute__((ext_vector_type(8))) short bf16x8;
typedef __attribute__((ext_vector_type(4))) float f32x4;

static __device__ __forceinline__ unsigned short f2bf(float f) {
  unsigned u = __float_as_uint(f);
  u += 0x7fffu + ((u >> 16) & 1u);   // round-to-nearest-even
  return (unsigned short)(u >> 16);
}

// ---------------- fused setup: zero counts | W->bf16 | p = W^T a -----------
__global__ __launch_bounds__(256) void k_setup(const float* __restrict__ W,
                                               const float* __restrict__ a,
                                               unsigned short* __restrict__ Wb,
                                               float* __restrict__ p_lo,
                                               float* __restrict__ p_hi,
                                               int* __restrict__ counts, int N, int nz) {
  int b = blockIdx.x;
  int t = threadIdx.x;
  if (b < nz) {
    int i = b * 256 + t;
    if (i < N) counts[i] = 0;
  } else if (b < nz + 64) {
    int i = (b - nz) * 256 + t;
    Wb[i] = f2bf(W[i]);
  } else {
    if (t < 128) {
      float lo = 0.f, hi = 0.f;
#pragma unroll 8
      for (int f = 0; f < 128; ++f) {
        float w = W[f * 128 + t];
        lo += w * a[f];
        hi += w * a[128 + f];
      }
      p_lo[t] = lo;
      p_hi[t] = hi;
    }
  }
}

// ---- fused worker: [0,SB) = edge scatter | [SB,..) = x->msgs + scores -----
__global__ __launch_bounds__(256) void k_work(const float* __restrict__ x,
                                              const float* __restrict__ p_lo,
                                              const float* __restrict__ p_hi,
                                              const unsigned short* __restrict__ Wb,
                                              unsigned short* __restrict__ msgs,
                                              float* __restrict__ s_src,
                                              float* __restrict__ s_dst, int N,
                                              const int* __restrict__ ei,
                                              int* __restrict__ counts,
                                              unsigned* __restrict__ e_in,
                                              unsigned* __restrict__ e_ovf, int E,
                                              int SB) {
  if ((int)blockIdx.x < SB) {
    // -------- scatter role: 1 edge/thread, split-bucket store --------
    int e = blockIdx.x * 256 + threadIdx.x;
    if (e >= E) return;
    int src = ei[e];
    int dst = ei[E + e];
    int pos = atomicAdd(&counts[dst], 1);
    if (pos < CAP_IN)
      e_in[(size_t)dst * CAP_IN + pos] = (unsigned)src;
    else if (pos < CAP)
      e_ovf[(size_t)dst * CAP_OVF + (pos - CAP_IN)] = (unsigned)src;
    return;
  }
  // ---------------- msg role: bf16 frags + fp32 dots + MFMA ----------------
  int bb = blockIdx.x - SB;
  int wave = (bb * 256 + (int)threadIdx.x) >> 6;
  int lane = threadIdx.x & 63;
  int base = wave * 16;
  if (base >= N) return;
  int q = lane >> 4, r = lane & 15;
  int node = base + r;
  const float* xrow = x + (size_t)node * 128 + q * 8;
  const float4* pl = (const float4*)p_lo;
  const float4* ph = (const float4*)p_hi;
  bf16x8 afrag[4];
  float lo = 0.f, hi = 0.f;
#pragma unroll
  for (int c = 0; c < 4; ++c) {
    float4 v0 = *(const float4*)(xrow + c * 32);
    float4 v1 = *(const float4*)(xrow + c * 32 + 4);
    int fi = q * 2 + c * 8;
    float4 a0 = pl[fi], a1 = pl[fi + 1];
    float4 b0 = ph[fi], b1 = ph[fi + 1];
    lo += v0.x * a0.x + v0.y * a0.y + v0.z * a0.z + v0.w * a0.w
        + v1.x * a1.x + v1.y * a1.y + v1.z * a1.z + v1.w * a1.w;
    hi += v0.x * b0.x + v0.y * b0.y + v0.z * b0.z + v0.w * b0.w
        + v1.x * b1.x + v1.y * b1.y + v1.z * b1.z + v1.w * b1.w;
    bf16x8 f;
    f[0] = (short)f2bf(v0.x); f[1] = (short)f2bf(v0.y);
    f[2] = (short)f2bf(v0.z); f[3] = (short)f2bf(v0.w);
    f[4] = (short)f2bf(v1.x); f[5] = (short)f2bf(v1.y);
    f[6] = (short)f2bf(v1.z); f[7] = (short)f2bf(v1.w);
    afrag[c] = f;
  }
  lo += __shfl_xor(lo, 16); lo += __shfl_xor(lo, 32);
  hi += __shfl_xor(hi, 16); hi += __shfl_xor(hi, 32);
  if (q == 0) { s_src[node] = lo; s_dst[node] = hi; }
#pragma unroll
  for (int ft = 0; ft < 8; ++ft) {
    const unsigned short* wrow = Wb + (size_t)(ft * 16 + r) * 128 + q * 8;
    f32x4 acc = {0.f, 0.f, 0.f, 0.f};
#pragma unroll
    for (int c = 0; c < 4; ++c) {
      bf16x8 bfrag = *(const bf16x8*)(wrow + c * 32);
      acc = __builtin_amdgcn_mfma_f32_16x16x32_bf16(afrag[c], bfrag, acc, 0, 0, 0);
    }
#pragma unroll
    for (int rr = 0; rr < 4; ++rr) {
      int n2 = base + q * 4 + rr;
      msgs[(size_t)n2 * 128 + ft * 16 + r] = f2bf(acc[rr]);
    }
  }
}

// ------- one wave per dst node: 16 edges in flight (4 groups x unroll 4) ---
__global__ __launch_bounds__(256) void k_agg(const unsigned short* __restrict__ msgs,
                                             const int* __restrict__ counts,
                                             const unsigned* __restrict__ e_in,
                                             const unsigned* __restrict__ e_ovf,
                                             const float* __restrict__ s_src,
                                             const float* __restrict__ s_dst,
                                             float* __restrict__ out, int N) {
  int wave = (blockIdx.x * 256 + threadIdx.x) >> 6;
  int lane = threadIdx.x & 63;
  if (wave >= N) return;
  int node = wave;
  int g = lane >> 4;
  int r = lane & 15;
  float sdn = s_dst[node];
  float zs = s_src[node] + sdn;
  zs = zs > 0.f ? zs : NEG_SLOPE * zs;
  float wself = expf(zs);
  float wg = (g == 0) ? wself : 0.f;
  float denom = wg;
  float acc[8];
  {
    const uint4* mrow = (const uint4*)(msgs + (size_t)node * 128);
    uint4 m = mrow[r];
    unsigned mm[4] = {m.x, m.y, m.z, m.w};
#pragma unroll
    for (int c = 0; c < 4; ++c) {
      acc[2 * c]     = wg * __uint_as_float(mm[c] << 16);
      acc[2 * c + 1] = wg * __uint_as_float(mm[c] & 0xffff0000u);
    }
  }
  int cnt = counts[node];
  cnt = cnt < CAP ? cnt : CAP;
  const unsigned* b_in = e_in + (size_t)node * CAP_IN;
  const unsigned* b_ovf = e_ovf + (size_t)node * CAP_OVF;
  int nIter = (cnt + 15) >> 4;   // 16 edges per iteration
  for (int it = 0; it < nIter; ++it) {
    int kb = it * 16 + g;
    bool v[4];
    unsigned e[4];
    uint4 m[4];
    float ss[4];
#pragma unroll
    for (int u = 0; u < 4; ++u) {
      int k = kb + u * 4;
      v[u] = k < cnt;
      int kc = v[u] ? k : 0;
      e[u] = (kc < CAP_IN) ? b_in[kc] : b_ovf[kc - CAP_IN];
    }
#pragma unroll
    for (int u = 0; u < 4; ++u)
      m[u] = ((const uint4*)(msgs + (size_t)e[u] * 128))[r];
#pragma unroll
    for (int u = 0; u < 4; ++u)
      ss[u] = s_src[e[u]];
#pragma unroll
    for (int u = 0; u < 4; ++u) {
      float z = ss[u] + sdn;
      z = z > 0.f ? z : NEG_SLOPE * z;
      float w = v[u] ? expf(z) : 0.f;
      unsigned mm[4] = {m[u].x, m[u].y, m[u].z, m[u].w};
#pragma unroll
      for (int c = 0; c < 4; ++c) {
        acc[2 * c]     += w * __uint_as_float(mm[c] << 16);
        acc[2 * c + 1] += w * __uint_as_float(mm[c] & 0xffff0000u);
      }
      denom += w;
    }
  }
#pragma unroll
  for (int mask = 16; mask < 64; mask <<= 1) {
#pragma unroll
    for (int j = 0; j < 8; ++j) acc[j] += __shfl_xor(acc[j], mask);
    denom += __shfl_xor(denom, mask);
  }
  if (g == 0) {
    float inv = 1.f / fmaxf(denom, 1e-12f);
    float4 o0 = {acc[0] * inv, acc[1] * inv, acc[2] * inv, acc[3] * inv};
    float4 o1 = {acc[4] * inv, acc[5] * inv, acc[6] * inv, acc[7] * inv};
    float4* orow = (float4*)(out + (size_t)node * 128);
    orow[r * 2] = o0;
    orow[r * 2 + 1] = o1;
  }
}

extern "C" void kernel_launch(void* const* d_in, const int* in_sizes, int n_in,
                              void* d_out, int out_size, void* d_ws, size_t ws_size,
                              hipStream_t stream) {
  const float* x = (const float*)d_in[0];
  const int* ei = (const int*)d_in[1];
  const float* W = (const float*)d_in[2];
  const float* a = (const float*)d_in[3];
  float* out = (float*)d_out;
  int N = in_sizes[0] / 128;
  int E = in_sizes[1] / 2;

  char* ws = (char*)d_ws;
  size_t off = 0;
  auto alloc = [&](size_t bytes) {
    off = (off + 255) & ~(size_t)255;
    void* p = ws + off;
    off += bytes;
    return p;
  };
  unsigned short* msgs = (unsigned short*)alloc((size_t)N * 128 * 2);
  float* s_src = (float*)alloc((size_t)N * 4);
  float* s_dst = (float*)alloc((size_t)N * 4);
  float* p_lo = (float*)alloc(512);
  float* p_hi = (float*)alloc(512);
  unsigned short* Wb = (unsigned short*)alloc(128 * 128 * 2);
  int* counts = (int*)alloc((size_t)N * 4);
  unsigned* e_in = (unsigned*)alloc((size_t)N * CAP_IN * 4);   // 64B-aligned lines
  unsigned* e_ovf = (unsigned*)alloc((size_t)N * CAP_OVF * 4);

  int nz = (N + 255) / 256;
  int waves = (N + 15) / 16;
  int SB = (E + 255) / 256;                     // scatter blocks (1 edge/thread)
  int MB = (waves + 3) / 4;                     // msg blocks
  k_setup<<<nz + 64 + 1, 256, 0, stream>>>(W, a, Wb, p_lo, p_hi, counts, N, nz);
  k_work<<<SB + MB, 256, 0, stream>>>(x, p_lo, p_hi, Wb, msgs, s_src, s_dst, N,
                                      ei, counts, e_in, e_ovf, E, SB);
  k_agg<<<(N + 3) / 4, 256, 0, stream>>>(msgs, counts, e_in, e_ovf, s_src, s_dst, out, N);
}

// Round 10
// 147.772 us; speedup vs baseline: 1.0972x; 1.0972x over previous
//
#include <hip/hip_runtime.h>

#define NEG_SLOPE 0.01f
#define CH 4096        // edges per pass-1 block
#define BSHIFT 9       // coarse bin = dst >> 9 (512 dsts per bin)
#define BINW 512
#define NBMAX 128      // max coarse bins (N <= 65536)

typedef __attribute__((ext_vector_type(8))) short bf16x8;
typedef __attribute__((ext_vector_type(4))) float f32x4;

static __device__ __forceinline__ unsigned short f2bf(float f) {
  unsigned u = __float_as_uint(f);
  u += 0x7fffu + ((u >> 16) & 1u);   // round-to-nearest-even
  return (unsigned short)(u >> 16);
}

// ---------------- setup: W->bf16 | p = W^T a | zero bin_cursor ------------
__global__ __launch_bounds__(256) void k_setup(const float* __restrict__ W,
                                               const float* __restrict__ a,
                                               unsigned short* __restrict__ Wb,
                                               float* __restrict__ p_lo,
                                               float* __restrict__ p_hi,
                                               int* __restrict__ bin_cursor) {
  int b = blockIdx.x;
  int t = threadIdx.x;
  if (b < 64) {
    int i = b * 256 + t;
    Wb[i] = f2bf(W[i]);
    if (b == 0 && t < NBMAX) bin_cursor[t] = 0;
  } else {
    if (t < 128) {
      float lo = 0.f, hi = 0.f;
#pragma unroll 8
      for (int f = 0; f < 128; ++f) {
        float w = W[f * 128 + t];
        lo += w * a[f];
        hi += w * a[128 + f];
      }
      p_lo[t] = lo;
      p_hi[t] = hi;
    }
  }
}

// ---- fused worker: [0,SB) = pass-1 radix partition | [SB,..) = msg --------
__global__ __launch_bounds__(256) void k_work(const float* __restrict__ x,
                                              const float* __restrict__ p_lo,
                                              const float* __restrict__ p_hi,
                                              const unsigned short* __restrict__ Wb,
                                              unsigned short* __restrict__ msgs,
                                              float* __restrict__ s_src,
                                              float* __restrict__ s_dst, int N,
                                              const int* __restrict__ ei,
                                              int* __restrict__ bin_cursor,
                                              int2* __restrict__ binbuf, int E,
                                              int SB, int BINCAP) {
  __shared__ int hist[NBMAX], base[NBMAX], cur[NBMAX], gbase[NBMAX];
  __shared__ int2 stage[CH];
  int t = threadIdx.x;
  if ((int)blockIdx.x < SB) {
    // ---------------- pass-1: partition 4096 edges by coarse bin ----------
    int e0 = blockIdx.x * CH;
    int cntE = E - e0; if (cntE > CH) cntE = CH;
    if (t < NBMAX) { hist[t] = 0; cur[t] = 0; }
    __syncthreads();
    int srcs[CH / 256], dsts[CH / 256];
#pragma unroll
    for (int j = 0; j < CH / 256; ++j) {
      int i = t + j * 256;
      if (i < cntE) {
        srcs[j] = ei[e0 + i];
        dsts[j] = ei[E + e0 + i];
        atomicAdd(&hist[dsts[j] >> BSHIFT], 1);
      }
    }
    __syncthreads();
    if (t < NBMAX) base[t] = hist[t];
    __syncthreads();
    for (int d = 1; d < NBMAX; d <<= 1) {
      int v = (t < NBMAX && t >= d) ? base[t - d] : 0;
      __syncthreads();
      if (t < NBMAX) base[t] += v;
      __syncthreads();
    }
    if (t < NBMAX) {
      base[t] -= hist[t];              // exclusive scan
      gbase[t] = hist[t] ? atomicAdd(&bin_cursor[t], hist[t]) : 0;
    }
    __syncthreads();
#pragma unroll
    for (int j = 0; j < CH / 256; ++j) {
      int i = t + j * 256;
      if (i < cntE) {
        int bin = dsts[j] >> BSHIFT;
        int p = base[bin] + atomicAdd(&cur[bin], 1);
        stage[p] = make_int2(srcs[j], dsts[j]);
      }
    }
    __syncthreads();
    // copy bin-sorted runs to global: sequential stores per run
    for (int i = t; i < cntE; i += 256) {
      int2 ed = stage[i];
      int bin = ed.y >> BSHIFT;
      int idx = gbase[bin] + (i - base[bin]);
      if (idx < BINCAP) binbuf[(size_t)bin * BINCAP + idx] = ed;
    }
    return;
  }
  // ---------------- msg role: bf16 frags + fp32 dots + MFMA ----------------
  int bb = blockIdx.x - SB;
  int wave = (bb * 256 + t) >> 6;
  int lane = t & 63;
  int baseN = wave * 16;
  if (baseN >= N) return;
  int q = lane >> 4, r = lane & 15;
  int node = baseN + r;
  const float* xrow = x + (size_t)node * 128 + q * 8;
  const float4* pl = (const float4*)p_lo;
  const float4* ph = (const float4*)p_hi;
  bf16x8 afrag[4];
  float lo = 0.f, hi = 0.f;
#pragma unroll
  for (int c = 0; c < 4; ++c) {
    float4 v0 = *(const float4*)(xrow + c * 32);
    float4 v1 = *(const float4*)(xrow + c * 32 + 4);
    int fi = q * 2 + c * 8;
    float4 a0 = pl[fi], a1 = pl[fi + 1];
    float4 b0 = ph[fi], b1 = ph[fi + 1];
    lo += v0.x * a0.x + v0.y * a0.y + v0.z * a0.z + v0.w * a0.w
        + v1.x * a1.x + v1.y * a1.y + v1.z * a1.z + v1.w * a1.w;
    hi += v0.x * b0.x + v0.y * b0.y + v0.z * b0.z + v0.w * b0.w
        + v1.x * b1.x + v1.y * b1.y + v1.z * b1.z + v1.w * b1.w;
    bf16x8 f;
    f[0] = (short)f2bf(v0.x); f[1] = (short)f2bf(v0.y);
    f[2] = (short)f2bf(v0.z); f[3] = (short)f2bf(v0.w);
    f[4] = (short)f2bf(v1.x); f[5] = (short)f2bf(v1.y);
    f[6] = (short)f2bf(v1.z); f[7] = (short)f2bf(v1.w);
    afrag[c] = f;
  }
  lo += __shfl_xor(lo, 16); lo += __shfl_xor(lo, 32);
  hi += __shfl_xor(hi, 16); hi += __shfl_xor(hi, 32);
  if (q == 0) { s_src[node] = lo; s_dst[node] = hi; }
#pragma unroll
  for (int ft = 0; ft < 8; ++ft) {
    const unsigned short* wrow = Wb + (size_t)(ft * 16 + r) * 128 + q * 8;
    f32x4 acc = {0.f, 0.f, 0.f, 0.f};
#pragma unroll
    for (int c = 0; c < 4; ++c) {
      bf16x8 bfrag = *(const bf16x8*)(wrow + c * 32);
      acc = __builtin_amdgcn_mfma_f32_16x16x32_bf16(afrag[c], bfrag, acc, 0, 0, 0);
    }
#pragma unroll
    for (int rr = 0; rr < 4; ++rr) {
      int n2 = baseN + q * 4 + rr;
      msgs[(size_t)n2 * 128 + ft * 16 + r] = f2bf(acc[rr]);
    }
  }
}

// ---- pass-2: per-bin counting sort -> CSR (one block per bin) -------------
__global__ __launch_bounds__(256) void k_pass2(const int2* __restrict__ binbuf,
                                               const int* __restrict__ bin_cursor,
                                               unsigned* __restrict__ csr,
                                               int2* __restrict__ meta,
                                               int N, int BINCAP) {
  __shared__ int hist[BINW], scanv[BINW], cur[BINW];
  __shared__ int tmp[256];
  int b = blockIdx.x, t = threadIdx.x;
  int cnt = bin_cursor[b]; if (cnt > BINCAP) cnt = BINCAP;
  const int2* bb = binbuf + (size_t)b * BINCAP;
  hist[t] = 0; hist[t + 256] = 0;
  __syncthreads();
  for (int i = t; i < cnt; i += 256)
    atomicAdd(&hist[bb[i].y & (BINW - 1)], 1);
  __syncthreads();
  int v0 = hist[2 * t], v1 = hist[2 * t + 1];
  tmp[t] = v0 + v1;
  __syncthreads();
  for (int d = 1; d < 256; d <<= 1) {
    int v = (t >= d) ? tmp[t - d] : 0;
    __syncthreads();
    tmp[t] += v;
    __syncthreads();
  }
  int excl = tmp[t] - (v0 + v1);
  scanv[2 * t] = excl;
  scanv[2 * t + 1] = excl + v0;
  cur[2 * t] = 0; cur[2 * t + 1] = 0;
  __syncthreads();
  int gb = b * BINCAP;
  for (int l = t; l < BINW; l += 256) {
    int dst = b * BINW + l;
    if (dst < N) meta[dst] = make_int2(gb + scanv[l], hist[l]);
  }
  __syncthreads();
  for (int i = t; i < cnt; i += 256) {
    int2 ed = bb[i];
    int l = ed.y & (BINW - 1);
    int p = atomicAdd(&cur[l], 1);
    csr[gb + scanv[l] + p] = (unsigned)ed.x;
  }
}

// ------- one wave per dst node: 16 edges in flight (4 groups x unroll 4) ---
__global__ __launch_bounds__(256) void k_agg(const unsigned short* __restrict__ msgs,
                                             const int2* __restrict__ meta,
                                             const unsigned* __restrict__ csr,
                                             const float* __restrict__ s_src,
                                             const float* __restrict__ s_dst,
                                             float* __restrict__ out, int N) {
  int wave = (blockIdx.x * 256 + threadIdx.x) >> 6;
  int lane = threadIdx.x & 63;
  if (wave >= N) return;
  int node = wave;
  int g = lane >> 4;
  int r = lane & 15;
  float sdn = s_dst[node];
  float zs = s_src[node] + sdn;
  zs = zs > 0.f ? zs : NEG_SLOPE * zs;
  float wself = expf(zs);
  float wg = (g == 0) ? wself : 0.f;
  float denom = wg;
  float acc[8];
  {
    const uint4* mrow = (const uint4*)(msgs + (size_t)node * 128);
    uint4 m = mrow[r];
    unsigned mm[4] = {m.x, m.y, m.z, m.w};
#pragma unroll
    for (int c = 0; c < 4; ++c) {
      acc[2 * c]     = wg * __uint_as_float(mm[c] << 16);
      acc[2 * c + 1] = wg * __uint_as_float(mm[c] & 0xffff0000u);
    }
  }
  int2 md = meta[node];
  int cnt = md.y;
  const unsigned* bucket = csr + md.x;
  int nIter = (cnt + 15) >> 4;   // 16 edges per iteration
  for (int it = 0; it < nIter; ++it) {
    int kb = it * 16 + g;
    bool v[4];
    unsigned e[4];
    uint4 m[4];
    float ss[4];
#pragma unroll
    for (int u = 0; u < 4; ++u) {
      int k = kb + u * 4;
      v[u] = k < cnt;
      e[u] = bucket[v[u] ? k : 0];
    }
#pragma unroll
    for (int u = 0; u < 4; ++u)
      m[u] = ((const uint4*)(msgs + (size_t)e[u] * 128))[r];
#pragma unroll
    for (int u = 0; u < 4; ++u)
      ss[u] = s_src[e[u]];
#pragma unroll
    for (int u = 0; u < 4; ++u) {
      float z = ss[u] + sdn;
      z = z > 0.f ? z : NEG_SLOPE * z;
      float w = v[u] ? expf(z) : 0.f;
      unsigned mm[4] = {m[u].x, m[u].y, m[u].z, m[u].w};
#pragma unroll
      for (int c = 0; c < 4; ++c) {
        acc[2 * c]     += w * __uint_as_float(mm[c] << 16);
        acc[2 * c + 1] += w * __uint_as_float(mm[c] & 0xffff0000u);
      }
      denom += w;
    }
  }
#pragma unroll
  for (int mask = 16; mask < 64; mask <<= 1) {
#pragma unroll
    for (int j = 0; j < 8; ++j) acc[j] += __shfl_xor(acc[j], mask);
    denom += __shfl_xor(denom, mask);
  }
  if (g == 0) {
    float inv = 1.f / fmaxf(denom, 1e-12f);
    float4 o0 = {acc[0] * inv, acc[1] * inv, acc[2] * inv, acc[3] * inv};
    float4 o1 = {acc[4] * inv, acc[5] * inv, acc[6] * inv, acc[7] * inv};
    float4* orow = (float4*)(out + (size_t)node * 128);
    orow[r * 2] = o0;
    orow[r * 2 + 1] = o1;
  }
}

extern "C" void kernel_launch(void* const* d_in, const int* in_sizes, int n_in,
                              void* d_out, int out_size, void* d_ws, size_t ws_size,
                              hipStream_t stream) {
  const float* x = (const float*)d_in[0];
  const int* ei = (const int*)d_in[1];
  const float* W = (const float*)d_in[2];
  const float* a = (const float*)d_in[3];
  float* out = (float*)d_out;
  int N = in_sizes[0] / 128;
  int E = in_sizes[1] / 2;

  int NB = (N + BINW - 1) >> BSHIFT;                 // 98 coarse bins
  int BINCAP = ((E / NB) + (E / NB) / 4 + 1024 + 255) & ~255;  // ~8.7k, 19+ sigma

  char* ws = (char*)d_ws;
  size_t off = 0;
  auto alloc = [&](size_t bytes) {
    off = (off + 255) & ~(size_t)255;
    void* p = ws + off;
    off += bytes;
    return p;
  };
  unsigned short* msgs = (unsigned short*)alloc((size_t)N * 128 * 2);
  float* s_src = (float*)alloc((size_t)N * 4);
  float* s_dst = (float*)alloc((size_t)N * 4);
  float* p_lo = (float*)alloc(512);
  float* p_hi = (float*)alloc(512);
  unsigned short* Wb = (unsigned short*)alloc(128 * 128 * 2);
  int* bin_cursor = (int*)alloc(NBMAX * 4);
  int2* binbuf = (int2*)alloc((size_t)NB * BINCAP * 8);
  unsigned* csr = (unsigned*)alloc((size_t)NB * BINCAP * 4);
  int2* meta = (int2*)alloc((size_t)N * 8);

  int waves = (N + 15) / 16;
  int SB = (E + CH - 1) / CH;                  // pass-1 blocks (147)
  int MB = (waves + 3) / 4;                    // msg blocks
  k_setup<<<65, 256, 0, stream>>>(W, a, Wb, p_lo, p_hi, bin_cursor);
  k_work<<<SB + MB, 256, 0, stream>>>(x, p_lo, p_hi, Wb, msgs, s_src, s_dst, N,
                                      ei, bin_cursor, binbuf, E, SB, BINCAP);
  k_pass2<<<NB, 256, 0, stream>>>(binbuf, bin_cursor, csr, meta, N, BINCAP);
  k_agg<<<(N + 3) / 4, 256, 0, stream>>>(msgs, meta, csr, s_src, s_dst, out, N);
}